// Round 8
// baseline (2089.059 us; speedup 1.0000x reference)
//
#include <hip/hip_runtime.h>
#include <stdint.h>

typedef unsigned short u16;
typedef float floatx4 __attribute__((ext_vector_type(4)));
typedef u16 u16x8 __attribute__((ext_vector_type(8)));
typedef u16 u16x4 __attribute__((ext_vector_type(4)));

__device__ __forceinline__ float bf2f(u16 u) {
    union { unsigned int i; float f; } v; v.i = ((unsigned int)u) << 16; return v.f;
}
__device__ __forceinline__ u16 f2bf(float f) {
    union { float f; unsigned int i; } v; v.f = f;
    unsigned int x = v.i;
    return (u16)((x + 0x7FFFu + ((x >> 16) & 1u)) >> 16);  // RNE
}

// ---------------------------------------------------------------------------
// Pure-VALU GEMM: C[M,1024] = A[M,1024] @ W[1024,1024]^T + bias, fp32 math.
//   ASRC 0: A fp32 direct; 1: A fp32 virtual concat kv1|kv2; 2: A bf16.
//   64x64 tile, 256 threads, 4x4 outputs/thread, K-tile 32, LDS pad 32->36.
// ---------------------------------------------------------------------------
template <int ASRC, bool OUT_F32>
__global__ __launch_bounds__(256) void gemm_valu(const void* __restrict__ A1v,
                                                 const void* __restrict__ A2v,
                                                 const float* __restrict__ W,
                                                 const float* __restrict__ bias,
                                                 void* __restrict__ Cv) {
    const int K = 1024, N = 1024;
    __shared__ float As[64 * 36];
    __shared__ float Ws[64 * 36];
    const int tid = threadIdx.x;
    const int tx = tid & 15, ty = tid >> 4;
    const int rowBase = blockIdx.y * 64;
    const int colBase = blockIdx.x * 64;

    const int srow = tid >> 2;
    const int scol = (tid & 3) * 8;
    const int g = rowBase + srow;

    const float* arow_f = nullptr;
    const u16*   arow_h = nullptr;
    if (ASRC == 0) {
        arow_f = (const float*)A1v + (long long)g * K;
    } else if (ASRC == 1) {
        int b = g / 3072, r = g - b * 3072;   // 64-row tiles never straddle the boundary
        arow_f = (r < 1024) ? ((const float*)A1v + ((long long)b * 1024 + r) * K)
                            : ((const float*)A2v + ((long long)b * 2048 + (r - 1024)) * K);
    } else {
        arow_h = (const u16*)A1v + (long long)g * K;
    }
    const float* wrow = W + (long long)(colBase + srow) * K;

    float acc[4][4];
    #pragma unroll
    for (int i = 0; i < 4; i++)
        #pragma unroll
        for (int j = 0; j < 4; j++) acc[i][j] = 0.f;

    for (int k0 = 0; k0 < K; k0 += 32) {
        if (ASRC == 2) {
            u16x8 av = *(const u16x8*)(arow_h + k0 + scol);
            floatx4 f0, f1;
            #pragma unroll
            for (int i = 0; i < 4; i++) { f0[i] = bf2f(av[i]); f1[i] = bf2f(av[4 + i]); }
            *(floatx4*)&As[srow * 36 + scol]     = f0;
            *(floatx4*)&As[srow * 36 + scol + 4] = f1;
        } else {
            *(floatx4*)&As[srow * 36 + scol]     = *(const floatx4*)(arow_f + k0 + scol);
            *(floatx4*)&As[srow * 36 + scol + 4] = *(const floatx4*)(arow_f + k0 + scol + 4);
        }
        *(floatx4*)&Ws[srow * 36 + scol]     = *(const floatx4*)(wrow + k0 + scol);
        *(floatx4*)&Ws[srow * 36 + scol + 4] = *(const floatx4*)(wrow + k0 + scol + 4);
        __syncthreads();

        #pragma unroll
        for (int k4 = 0; k4 < 32; k4 += 4) {
            floatx4 a4[4], w4[4];
            #pragma unroll
            for (int i = 0; i < 4; i++) a4[i] = *(const floatx4*)&As[(ty * 4 + i) * 36 + k4];
            #pragma unroll
            for (int j = 0; j < 4; j++) w4[j] = *(const floatx4*)&Ws[(tx * 4 + j) * 36 + k4];
            #pragma unroll
            for (int i = 0; i < 4; i++)
                #pragma unroll
                for (int j = 0; j < 4; j++)
                    acc[i][j] += a4[i][0] * w4[j][0] + a4[i][1] * w4[j][1]
                               + a4[i][2] * w4[j][2] + a4[i][3] * w4[j][3];
        }
        __syncthreads();
    }

    #pragma unroll
    for (int i = 0; i < 4; i++) {
        int row = rowBase + ty * 4 + i;
        #pragma unroll
        for (int j = 0; j < 4; j++) {
            int col = colBase + tx * 4 + j;
            float v = acc[i][j] + bias[col];
            if (OUT_F32) ((float*)Cv)[(long long)row * N + col] = v;
            else         ((u16*)Cv)[(long long)row * N + col] = f2bf(v);
        }
    }
}

// ---------------------------------------------------------------------------
// Flash attention. Block = (b, h, 64 query rows). 4 waves x 16 rows.
// q/k/v bf16 in, ctx bf16 out. fp32 VALU math.
// Tripled causal mask: key (s mod 1024) <= l.
// Ctx may alias Q: each block reads exactly the Q region it writes (rows
// l0..l0+63, cols h*64..h*64+63), staged to LDS before any write; regions are
// disjoint across blocks.
// ---------------------------------------------------------------------------
__global__ __launch_bounds__(256) void attn_kernel(const u16* __restrict__ Q,
                                                   const u16* __restrict__ Kb,
                                                   const u16* __restrict__ Vb,
                                                   u16* __restrict__ Ctx) {
    __shared__ float Qs[64 * 64];      // 16 KB
    __shared__ u16   Ks[64 * 72];      // 9 KB, pad 64->72
    __shared__ u16   Vt[64 * 72];      // 9 KB, TRANSPOSED: Vt[dim][key]
    __shared__ float Ps[4 * 16 * 64];  // 16 KB, per-wave P tiles
    const int tid = threadIdx.x;
    const int wave = tid >> 6, lane = tid & 63;
    const int qt = blockIdx.x & 15;
    const int h  = (blockIdx.x >> 4) & 15;
    const int b  = blockIdx.x >> 8;
    const int l0 = qt * 64;

    {   // stage Q tile (bf16 -> fp32 LDS)
        int row = tid >> 2, db = (tid & 3) * 16;
        const u16* src = Q + ((long long)(b * 1024 + l0 + row)) * 1024 + h * 64 + db;
        u16x8 u0 = *(const u16x8*)src;
        u16x8 u1 = *(const u16x8*)(src + 8);
        float f[16];
        #pragma unroll
        for (int i = 0; i < 8; i++) { f[i] = bf2f(u0[i]); f[8 + i] = bf2f(u1[i]); }
        #pragma unroll
        for (int i = 0; i < 16; i += 4) {
            floatx4 t4; t4[0] = f[i]; t4[1] = f[i+1]; t4[2] = f[i+2]; t4[3] = f[i+3];
            *(floatx4*)&Qs[row * 64 + db + i] = t4;
        }
    }

    float m_i[16], l_i[16], o_i[16];
    #pragma unroll
    for (int r = 0; r < 16; r++) { m_i[r] = -1e30f; l_i[r] = 0.f; o_i[r] = 0.f; }
    const float scale = 0.125f;  // 1/sqrt(64)

    for (int seg = 0; seg < 3; seg++) {
        for (int t = 0; t <= qt; t++) {
            __syncthreads();  // protect prior Ks/Vt/Ps readers (and publish Qs on iter 0)
            {   // stage K, V (V transposed) for keys [t*64, t*64+64)
                int key = tid >> 2, db = (tid & 3) * 16;
                long long rowi = (long long)(b * 3072 + seg * 1024 + t * 64 + key) * 1024 + h * 64 + db;
                u16x8 k0v = *(const u16x8*)(Kb + rowi);
                u16x8 k1v = *(const u16x8*)(Kb + rowi + 8);
                u16x8 v0v = *(const u16x8*)(Vb + rowi);
                u16x8 v1v = *(const u16x8*)(Vb + rowi + 8);
                *(u16x8*)&Ks[key * 72 + db]     = k0v;
                *(u16x8*)&Ks[key * 72 + db + 8] = k1v;
                #pragma unroll
                for (int i = 0; i < 8; i++) {
                    Vt[(db + i) * 72 + key]     = v0v[i];
                    Vt[(db + 8 + i) * 72 + key] = v1v[i];
                }
            }
            __syncthreads();

            // QK^T: lane = key index
            float sc[16];
            #pragma unroll
            for (int r = 0; r < 16; r++) sc[r] = 0.f;
            for (int d8 = 0; d8 < 64; d8 += 8) {
                u16x8 k8 = *(const u16x8*)&Ks[lane * 72 + d8];
                float kf[8];
                #pragma unroll
                for (int i = 0; i < 8; i++) kf[i] = bf2f(k8[i]);
                #pragma unroll
                for (int r = 0; r < 16; r++) {
                    const floatx4* qp = (const floatx4*)&Qs[(wave * 16 + r) * 64 + d8];
                    floatx4 qa = qp[0], qb = qp[1];
                    sc[r] += qa[0]*kf[0] + qa[1]*kf[1] + qa[2]*kf[2] + qa[3]*kf[3]
                           + qb[0]*kf[4] + qb[1]*kf[5] + qb[2]*kf[6] + qb[3]*kf[7];
                }
            }

            // online softmax per row
            const bool diag = (t == qt);
            #pragma unroll
            for (int r = 0; r < 16; r++) {
                int lrow = wave * 16 + r;
                float s = sc[r] * scale;
                if (diag && lane > lrow) s = -1e30f;
                float mx = s;
                #pragma unroll
                for (int off = 32; off >= 1; off >>= 1) mx = fmaxf(mx, __shfl_xor(mx, off));
                float m_new = fmaxf(m_i[r], mx);
                float p = __expf(s - m_new);
                if (diag && lane > lrow) p = 0.f;
                float ps = p;
                #pragma unroll
                for (int off = 32; off >= 1; off >>= 1) ps += __shfl_xor(ps, off);
                float alpha = __expf(m_i[r] - m_new);
                m_i[r] = m_new;
                l_i[r] = l_i[r] * alpha + ps;
                o_i[r] *= alpha;
                Ps[(wave * 16 + r) * 64 + lane] = p;
            }

            __syncthreads();  // publish Ps writes before cross-lane reads

            // P @ V: lane = dim index
            for (int s8 = 0; s8 < 64; s8 += 8) {
                u16x8 v8 = *(const u16x8*)&Vt[lane * 72 + s8];
                float vf[8];
                #pragma unroll
                for (int i = 0; i < 8; i++) vf[i] = bf2f(v8[i]);
                #pragma unroll
                for (int r = 0; r < 16; r++) {
                    const floatx4* pp = (const floatx4*)&Ps[(wave * 16 + r) * 64 + s8];
                    floatx4 pa = pp[0], pb = pp[1];
                    o_i[r] += pa[0]*vf[0] + pa[1]*vf[1] + pa[2]*vf[2] + pa[3]*vf[3]
                            + pb[0]*vf[4] + pb[1]*vf[5] + pb[2]*vf[6] + pb[3]*vf[7];
                }
            }
        }
    }

    #pragma unroll
    for (int r = 0; r < 16; r++) {
        int l = l0 + wave * 16 + r;
        float o = o_i[r] / l_i[r];
        Ctx[((long long)(b * 1024 + l)) * 1024 + h * 64 + lane] = f2bf(o);
    }
}

// ---------------------------------------------------------------------------
// residual + LayerNorm + mask. One block per row (1024 cols).
// ALL fp32 in, **fp32 out** (round-8 fix: output dtype is fp32).
// ---------------------------------------------------------------------------
__global__ __launch_bounds__(256) void ln_kernel(const float* __restrict__ AO,
                                                 const float* __restrict__ HQ,
                                                 const float* __restrict__ g,
                                                 const float* __restrict__ bb,
                                                 const float* __restrict__ mask,
                                                 float* __restrict__ Out) {
    const int row = blockIdx.x;   // 0..2047
    const int t = threadIdx.x;
    const int base = row * 1024 + t * 4;
    floatx4 a  = *(const floatx4*)&AO[base];
    floatx4 hq = *(const floatx4*)&HQ[base];
    float x[4];
    #pragma unroll
    for (int i = 0; i < 4; i++) x[i] = a[i] + hq[i];
    float s = x[0] + x[1] + x[2] + x[3];
    float ss = x[0]*x[0] + x[1]*x[1] + x[2]*x[2] + x[3]*x[3];
    #pragma unroll
    for (int off = 32; off >= 1; off >>= 1) { s += __shfl_xor(s, off); ss += __shfl_xor(ss, off); }
    __shared__ float smem[8];
    int wave = t >> 6, lane = t & 63;
    if (lane == 0) { smem[wave] = s; smem[4 + wave] = ss; }
    __syncthreads();
    s  = smem[0] + smem[1] + smem[2] + smem[3];
    ss = smem[4] + smem[5] + smem[6] + smem[7];
    float mu  = s * (1.f / 1024.f);
    float var = ss * (1.f / 1024.f) - mu * mu;
    float rs  = rsqrtf(var + 1e-5f);
    float mv  = mask[row];
    floatx4 g4 = *(const floatx4*)&g[t * 4];
    floatx4 b4 = *(const floatx4*)&bb[t * 4];
    floatx4 y4;
    #pragma unroll
    for (int i = 0; i < 4; i++) {
        y4[i] = ((x[i] - mu) * rs * g4[i] + b4[i]) * mv;
    }
    *(floatx4*)&Out[base] = y4;
}

// ---------------------------------------------------------------------------
// Workspace: 28 MB total.
//   ws+0      q_b (4 MB bf16) -> reused in-place as ctx by attn_kernel
//   ws+4 MB   k_b (12 MB bf16) -> reused as ao (fp32 8 MB) after attention
//   ws+16 MB  v_b (12 MB bf16)
// ---------------------------------------------------------------------------
extern "C" void kernel_launch(void* const* d_in, const int* in_sizes, int n_in,
                              void* d_out, int out_size, void* d_ws, size_t ws_size,
                              hipStream_t stream) {
    (void)in_sizes; (void)n_in; (void)out_size; (void)ws_size;
    const float* h_q   = (const float*)d_in[0];
    const float* h_kv1 = (const float*)d_in[1];
    const float* h_kv2 = (const float*)d_in[2];
    const float* maskp = (const float*)d_in[3];
    const float* win   = (const float*)d_in[4];
    const float* binp  = (const float*)d_in[5];
    const float* wout  = (const float*)d_in[6];
    const float* bout  = (const float*)d_in[7];
    const float* ln_g  = (const float*)d_in[8];
    const float* ln_b  = (const float*)d_in[9];
    float* outp = (float*)d_out;   // fp32 output (round-8 fix)

    char* ws = (char*)d_ws;
    const size_t MB = 1024 * 1024;
    u16*   q_b   = (u16*)(ws);             // 4 MB; becomes ctx in-place
    u16*   k_b   = (u16*)(ws + 4 * MB);    // 12 MB; dead after attn
    u16*   v_b   = (u16*)(ws + 16 * MB);   // 12 MB
    u16*   ctx_b = q_b;                    // alias (safe: see attn_kernel note)
    float* ao    = (float*)(ws + 4 * MB);  // overwrites k_b after attn (8 MB)

    gemm_valu<0, false><<<dim3(16, 32), 256, 0, stream>>>(h_q,   nullptr, win,                   binp,        (void*)q_b);
    gemm_valu<1, false><<<dim3(16, 96), 256, 0, stream>>>(h_kv1, h_kv2,   win + 1024 * 1024,     binp + 1024, (void*)k_b);
    gemm_valu<1, false><<<dim3(16, 96), 256, 0, stream>>>(h_kv1, h_kv2,   win + 2 * 1024 * 1024, binp + 2048, (void*)v_b);
    attn_kernel<<<512, 256, 0, stream>>>(q_b, k_b, v_b, ctx_b);
    gemm_valu<2, true><<<dim3(16, 32), 256, 0, stream>>>(ctx_b, nullptr, wout, bout, (void*)ao);
    ln_kernel<<<2048, 256, 0, stream>>>(ao, h_q, ln_g, ln_b, maskp, outp);
}

// Round 9
// 372.999 us; speedup vs baseline: 5.6007x; 5.6007x over previous
//
#include <hip/hip_runtime.h>
#include <stdint.h>

typedef unsigned short u16;
typedef __bf16 bf16x8 __attribute__((ext_vector_type(8)));
typedef float floatx4 __attribute__((ext_vector_type(4)));
typedef u16 u16x8 __attribute__((ext_vector_type(8)));

__device__ __forceinline__ float bf2f(u16 u) {
    union { unsigned int i; float f; } v; v.i = ((unsigned int)u) << 16; return v.f;
}
__device__ __forceinline__ u16 f2bf(float f) {
    union { float f; unsigned int i; } v; v.f = f;
    unsigned int x = v.i;
    return (u16)((x + 0x7FFFu + ((x >> 16) & 1u)) >> 16);  // RNE
}

// ---------------------------------------------------------------------------
// MFMA GEMM: C[M,1024] = A[M,1024] @ W[1024,1024]^T + bias.
//   ASRC 0: A fp32 direct; 1: A fp32 virtual concat kv1|kv2; 2: A bf16.
//   W,bias fp32. Staged to LDS as bf16; mfma_f32_16x16x32_bf16; fp32 acc.
//   64x64 tile, BK=32, 4 waves x (2x2 16x16 subtiles).
// ---------------------------------------------------------------------------
template <int ASRC, bool OUT_F32>
__global__ __launch_bounds__(256) void gemm_bt(const void* __restrict__ A1v,
                                               const void* __restrict__ A2v,
                                               const float* __restrict__ W,
                                               const float* __restrict__ bias,
                                               void* __restrict__ Cv) {
    const int K = 1024, N = 1024;
    __shared__ u16 As[64 * 40];   // pad 32->40 (80B row stride, 16B-aligned frags)
    __shared__ u16 Bs[64 * 40];
    const int tid = threadIdx.x;
    const int wave = tid >> 6, lane = tid & 63;
    const int lane16 = lane & 15, quad = lane >> 4;
    const int rowBase = blockIdx.y * 64;
    const int colBase = blockIdx.x * 64;
    const int wr = (wave >> 1) * 32, wc = (wave & 1) * 32;
    floatx4 acc00 = {0.f, 0.f, 0.f, 0.f}, acc01 = acc00, acc10 = acc00, acc11 = acc00;

    const int srow = tid >> 2;        // 0..63
    const int scol = (tid & 3) * 8;   // 0,8,16,24
    const int g = rowBase + srow;

    const float* arow_f = nullptr;
    const u16*   arow_h = nullptr;
    if (ASRC == 0) {
        arow_f = (const float*)A1v + (long long)g * K;
    } else if (ASRC == 1) {
        int b = g / 3072, r = g - b * 3072;   // 64-row tiles never straddle the boundary
        arow_f = (r < 1024) ? ((const float*)A1v + ((long long)b * 1024 + r) * K)
                            : ((const float*)A2v + ((long long)b * 2048 + (r - 1024)) * K);
    } else {
        arow_h = (const u16*)A1v + (long long)g * K;
    }
    const float* wrow = W + (long long)(colBase + srow) * K;

    for (int k0 = 0; k0 < K; k0 += 32) {
        u16x8 av, wv;
        if (ASRC == 2) {
            av = *(const u16x8*)(arow_h + k0 + scol);
        } else {
            floatx4 f0 = *(const floatx4*)(arow_f + k0 + scol);
            floatx4 f1 = *(const floatx4*)(arow_f + k0 + scol + 4);
            #pragma unroll
            for (int i = 0; i < 4; i++) { av[i] = f2bf(f0[i]); av[4 + i] = f2bf(f1[i]); }
        }
        {
            floatx4 w0 = *(const floatx4*)(wrow + k0 + scol);
            floatx4 w1 = *(const floatx4*)(wrow + k0 + scol + 4);
            #pragma unroll
            for (int i = 0; i < 4; i++) { wv[i] = f2bf(w0[i]); wv[4 + i] = f2bf(w1[i]); }
        }
        *(u16x8*)&As[srow * 40 + scol] = av;
        *(u16x8*)&Bs[srow * 40 + scol] = wv;
        __syncthreads();
        u16x8 a0 = *(const u16x8*)&As[(wr + lane16) * 40 + quad * 8];
        u16x8 a1 = *(const u16x8*)&As[(wr + 16 + lane16) * 40 + quad * 8];
        u16x8 b0 = *(const u16x8*)&Bs[(wc + lane16) * 40 + quad * 8];
        u16x8 b1 = *(const u16x8*)&Bs[(wc + 16 + lane16) * 40 + quad * 8];
        bf16x8 af0 = __builtin_bit_cast(bf16x8, a0);
        bf16x8 af1 = __builtin_bit_cast(bf16x8, a1);
        bf16x8 bf0 = __builtin_bit_cast(bf16x8, b0);
        bf16x8 bf1 = __builtin_bit_cast(bf16x8, b1);
        acc00 = __builtin_amdgcn_mfma_f32_16x16x32_bf16(af0, bf0, acc00, 0, 0, 0);
        acc01 = __builtin_amdgcn_mfma_f32_16x16x32_bf16(af0, bf1, acc01, 0, 0, 0);
        acc10 = __builtin_amdgcn_mfma_f32_16x16x32_bf16(af1, bf0, acc10, 0, 0, 0);
        acc11 = __builtin_amdgcn_mfma_f32_16x16x32_bf16(af1, bf1, acc11, 0, 0, 0);
        __syncthreads();
    }

    // C/D layout (m89-verified): col = lane&15, row = quad*4 + reg.
    floatx4 accs[2][2] = {{acc00, acc01}, {acc10, acc11}};
    #pragma unroll
    for (int mi = 0; mi < 2; mi++)
        #pragma unroll
        for (int ni = 0; ni < 2; ni++)
            #pragma unroll
            for (int r = 0; r < 4; r++) {
                int row = rowBase + wr + mi * 16 + quad * 4 + r;
                int col = colBase + wc + ni * 16 + lane16;
                float v = accs[mi][ni][r] + bias[col];
                if (OUT_F32) ((float*)Cv)[(long long)row * N + col] = v;
                else         ((u16*)Cv)[(long long)row * N + col] = f2bf(v);
            }
}

// ---------------------------------------------------------------------------
// MFMA flash attention. Block = (b, h, 64 q rows); wave = 16 q rows.
// Computes S^T = K @ Q^T so the q index lands in lane&15 (C-layout col):
// softmax stats reduce with 2 shuffles, alpha/l are per-lane scalars.
// Then O^T = V^T @ P^T (A = Vt from LDS, B = P from wave-private LDS).
// q/k/v bf16, ctx bf16. Ctx may alias Q (Q read to regs before any write;
// per-block regions disjoint).
// ---------------------------------------------------------------------------
__global__ __launch_bounds__(256) void attn_mfma(const u16* __restrict__ Q,
                                                 const u16* __restrict__ Kb,
                                                 const u16* __restrict__ Vb,
                                                 u16* __restrict__ Ctx) {
    __shared__ u16 Vt[64 * 80];        // 10 KB  Vt[d][key], pad 80 (160B rows)
    __shared__ u16 Ps[4][16 * 80];     // 10 KB  per-wave P[q][key], pad 80
    const int tid = threadIdx.x;
    const int wave = tid >> 6, lane = tid & 63;
    const int lane16 = lane & 15, quad = lane >> 4;
    const int qt = blockIdx.x & 15;
    const int h  = (blockIdx.x >> 4) & 15;
    const int b  = blockIdx.x >> 8;
    const int l0 = qt * 64;
    const int wq = wave * 16;
    const float scale = 0.125f;  // 1/sqrt(64)

    // Q B-frags: B[n=q=lane16][k=c*32+quad*8+j] -> direct global 16B loads.
    bf16x8 qf[2];
    {
        const u16* qrow = Q + ((long long)(b * 1024 + l0 + wq + lane16)) * 1024 + h * 64;
        qf[0] = __builtin_bit_cast(bf16x8, *(const u16x8*)(qrow + quad * 8));
        qf[1] = __builtin_bit_cast(bf16x8, *(const u16x8*)(qrow + 32 + quad * 8));
    }

    float m_i = -1e30f, l_i = 0.f;     // stats for q col = lane16
    floatx4 o_acc[4];                  // O^T: d = mi*16 + quad*4 + r, q = lane16
    #pragma unroll
    for (int mi = 0; mi < 4; mi++) o_acc[mi] = floatx4{0.f, 0.f, 0.f, 0.f};

    for (int seg = 0; seg < 3; seg++) {
        for (int t = 0; t <= qt; t++) {
            const long long kvbase = ((long long)(b * 3072 + seg * 1024 + t * 64)) * 1024 + h * 64;
            __syncthreads();  // protect previous iteration's Vt/Ps readers
            {   // stage V transposed: Vt[d][key]
                int key = tid >> 2, db = (tid & 3) * 16;
                const u16* src = Vb + kvbase + (long long)key * 1024 + db;
                u16x8 v0v = *(const u16x8*)src;
                u16x8 v1v = *(const u16x8*)(src + 8);
                #pragma unroll
                for (int i = 0; i < 8; i++) {
                    Vt[(db + i) * 80 + key]     = v0v[i];
                    Vt[(db + 8 + i) * 80 + key] = v1v[i];
                }
            }
            __syncthreads();

            // S^T = K @ Q^T : A[m=key] = K rows (direct global), B = qf.
            floatx4 sacc[4];
            #pragma unroll
            for (int mi = 0; mi < 4; mi++) sacc[mi] = floatx4{0.f, 0.f, 0.f, 0.f};
            #pragma unroll
            for (int c = 0; c < 2; c++) {
                #pragma unroll
                for (int mi = 0; mi < 4; mi++) {
                    const u16* krow = Kb + kvbase + (long long)(mi * 16 + lane16) * 1024 + c * 32 + quad * 8;
                    bf16x8 kf = __builtin_bit_cast(bf16x8, *(const u16x8*)krow);
                    sacc[mi] = __builtin_amdgcn_mfma_f32_16x16x32_bf16(kf, qf[c], sacc[mi], 0, 0, 0);
                }
            }

            // scale + causal mask (diag tile: key_local > q_local masked)
            const bool diag = (t == qt);
            const int qloc = wq + lane16;
            float tmax = -1e30f;
            #pragma unroll
            for (int mi = 0; mi < 4; mi++)
                #pragma unroll
                for (int r = 0; r < 4; r++) {
                    float s = sacc[mi][r] * scale;
                    if (diag && (mi * 16 + quad * 4 + r) > qloc) s = -1e30f;
                    sacc[mi][r] = s;
                    tmax = fmaxf(tmax, s);
                }
            tmax = fmaxf(tmax, __shfl_xor(tmax, 16));
            tmax = fmaxf(tmax, __shfl_xor(tmax, 32));
            float m_new = fmaxf(m_i, tmax);
            float alpha = __expf(m_i - m_new);
            float psum = 0.f;
            #pragma unroll
            for (int mi = 0; mi < 4; mi++)
                #pragma unroll
                for (int r = 0; r < 4; r++) {
                    float p = __expf(sacc[mi][r] - m_new);
                    psum += p;
                    Ps[wave][lane16 * 80 + mi * 16 + quad * 4 + r] = f2bf(p);
                }
            psum += __shfl_xor(psum, 16);
            psum += __shfl_xor(psum, 32);
            m_i = m_new;
            l_i = l_i * alpha + psum;
            #pragma unroll
            for (int mi = 0; mi < 4; mi++)
                #pragma unroll
                for (int r = 0; r < 4; r++) o_acc[mi][r] *= alpha;

            __syncthreads();  // publish Ps (cross-lane) before B-frag reads

            // O^T += V^T @ P^T : A = Vt[d][key] frags, B = Ps[q][key] frags.
            #pragma unroll
            for (int c = 0; c < 2; c++) {
                bf16x8 pf = __builtin_bit_cast(bf16x8,
                    *(const u16x8*)&Ps[wave][lane16 * 80 + c * 32 + quad * 8]);
                #pragma unroll
                for (int mi = 0; mi < 4; mi++) {
                    bf16x8 vf = __builtin_bit_cast(bf16x8,
                        *(const u16x8*)&Vt[(mi * 16 + lane16) * 80 + c * 32 + quad * 8]);
                    o_acc[mi] = __builtin_amdgcn_mfma_f32_16x16x32_bf16(vf, pf, o_acc[mi], 0, 0, 0);
                }
            }
        }
    }

    // O^T store: d = mi*16+quad*4+r, q = lane16 (scalar u16 stores, once).
    const float inv_l = 1.0f / l_i;
    long long crow = ((long long)(b * 1024 + l0 + wq + lane16)) * 1024 + h * 64;
    #pragma unroll
    for (int mi = 0; mi < 4; mi++)
        #pragma unroll
        for (int r = 0; r < 4; r++)
            Ctx[crow + mi * 16 + quad * 4 + r] = f2bf(o_acc[mi][r] * inv_l);
}

// ---------------------------------------------------------------------------
// residual + LayerNorm + mask. One block per row. fp32 in, fp32 out.
// ---------------------------------------------------------------------------
__global__ __launch_bounds__(256) void ln_kernel(const float* __restrict__ AO,
                                                 const float* __restrict__ HQ,
                                                 const float* __restrict__ g,
                                                 const float* __restrict__ bb,
                                                 const float* __restrict__ mask,
                                                 float* __restrict__ Out) {
    const int row = blockIdx.x;   // 0..2047
    const int t = threadIdx.x;
    const int base = row * 1024 + t * 4;
    floatx4 a  = *(const floatx4*)&AO[base];
    floatx4 hq = *(const floatx4*)&HQ[base];
    float x[4];
    #pragma unroll
    for (int i = 0; i < 4; i++) x[i] = a[i] + hq[i];
    float s = x[0] + x[1] + x[2] + x[3];
    float ss = x[0]*x[0] + x[1]*x[1] + x[2]*x[2] + x[3]*x[3];
    #pragma unroll
    for (int off = 32; off >= 1; off >>= 1) { s += __shfl_xor(s, off); ss += __shfl_xor(ss, off); }
    __shared__ float smem[8];
    int wave = t >> 6, lane = t & 63;
    if (lane == 0) { smem[wave] = s; smem[4 + wave] = ss; }
    __syncthreads();
    s  = smem[0] + smem[1] + smem[2] + smem[3];
    ss = smem[4] + smem[5] + smem[6] + smem[7];
    float mu  = s * (1.f / 1024.f);
    float var = ss * (1.f / 1024.f) - mu * mu;
    float rs  = rsqrtf(var + 1e-5f);
    float mv  = mask[row];
    floatx4 g4 = *(const floatx4*)&g[t * 4];
    floatx4 b4 = *(const floatx4*)&bb[t * 4];
    floatx4 y4;
    #pragma unroll
    for (int i = 0; i < 4; i++) y4[i] = ((x[i] - mu) * rs * g4[i] + b4[i]) * mv;
    *(floatx4*)&Out[base] = y4;
}

// ---------------------------------------------------------------------------
// Workspace: 28 MB total.
//   ws+0      q_b (4 MB bf16) -> reused in-place as ctx by attn_mfma
//   ws+4 MB   k_b (12 MB bf16) -> reused as ao (fp32 8 MB) after attention
//   ws+16 MB  v_b (12 MB bf16)
// ---------------------------------------------------------------------------
extern "C" void kernel_launch(void* const* d_in, const int* in_sizes, int n_in,
                              void* d_out, int out_size, void* d_ws, size_t ws_size,
                              hipStream_t stream) {
    (void)in_sizes; (void)n_in; (void)out_size; (void)ws_size;
    const float* h_q   = (const float*)d_in[0];
    const float* h_kv1 = (const float*)d_in[1];
    const float* h_kv2 = (const float*)d_in[2];
    const float* maskp = (const float*)d_in[3];
    const float* win   = (const float*)d_in[4];
    const float* binp  = (const float*)d_in[5];
    const float* wout  = (const float*)d_in[6];
    const float* bout  = (const float*)d_in[7];
    const float* ln_g  = (const float*)d_in[8];
    const float* ln_b  = (const float*)d_in[9];
    float* outp = (float*)d_out;

    char* ws = (char*)d_ws;
    const size_t MB = 1024 * 1024;
    u16*   q_b   = (u16*)(ws);             // 4 MB; becomes ctx in-place
    u16*   k_b   = (u16*)(ws + 4 * MB);    // 12 MB; dead after attn
    u16*   v_b   = (u16*)(ws + 16 * MB);   // 12 MB
    u16*   ctx_b = q_b;                    // alias (safe: see attn_mfma note)
    float* ao    = (float*)(ws + 4 * MB);  // overwrites k_b after attn (8 MB)

    gemm_bt<0, false><<<dim3(16, 32), 256, 0, stream>>>(h_q,   nullptr, win,                   binp,        (void*)q_b);
    gemm_bt<1, false><<<dim3(16, 96), 256, 0, stream>>>(h_kv1, h_kv2,   win + 1024 * 1024,     binp + 1024, (void*)k_b);
    gemm_bt<1, false><<<dim3(16, 96), 256, 0, stream>>>(h_kv1, h_kv2,   win + 2 * 1024 * 1024, binp + 2048, (void*)v_b);
    attn_mfma<<<512, 256, 0, stream>>>(q_b, k_b, v_b, ctx_b);
    gemm_bt<2, true><<<dim3(16, 32), 256, 0, stream>>>(ctx_b, nullptr, wout, bout, (void*)ao);
    ln_kernel<<<2048, 256, 0, stream>>>(ao, h_q, ln_g, ln_b, maskp, outp);
}

// Round 11
// 345.693 us; speedup vs baseline: 6.0431x; 1.0790x over previous
//
#include <hip/hip_runtime.h>
#include <stdint.h>

typedef unsigned short u16;
typedef __bf16 bf16x8 __attribute__((ext_vector_type(8)));
typedef float floatx4 __attribute__((ext_vector_type(4)));
typedef u16 u16x8 __attribute__((ext_vector_type(8)));

__device__ __forceinline__ float bf2f(u16 u) {
    union { unsigned int i; float f; } v; v.i = ((unsigned int)u) << 16; return v.f;
}
__device__ __forceinline__ u16 f2bf(float f) {
    union { float f; unsigned int i; } v; v.f = f;
    unsigned int x = v.i;
    return (u16)((x + 0x7FFFu + ((x >> 16) & 1u)) >> 16);  // RNE
}

// ---------------------------------------------------------------------------
// MFMA GEMM, 128x64 tile: C[M,1024] = A[M,1024] @ W^T + bias.
//   W fp32 (converted to bf16 during LDS staging). A: 0 = fp32 direct,
//   1 = fp32 concat kv1|kv2, 2 = bf16. BK=32, 4 waves in 2x2 (64x32 each).
// ---------------------------------------------------------------------------
template <int ASRC, bool OUT_F32>
__global__ __launch_bounds__(256) void gemm128(const void* __restrict__ A1v,
                                               const void* __restrict__ A2v,
                                               const float* __restrict__ W,
                                               const float* __restrict__ bias,
                                               void* __restrict__ Cv) {
    const int K = 1024, N = 1024;
    __shared__ u16 As[128 * 40];
    __shared__ u16 Bs[64 * 40];
    const int tid = threadIdx.x;
    const int wave = tid >> 6, lane = tid & 63;
    const int lane16 = lane & 15, quad = lane >> 4;
    const int rowBase = blockIdx.y * 128;
    const int colBase = blockIdx.x * 64;
    const int wm = (wave >> 1) * 64, wn = (wave & 1) * 32;

    floatx4 acc[4][2];
    #pragma unroll
    for (int am = 0; am < 4; am++)
        #pragma unroll
        for (int bn = 0; bn < 2; bn++) acc[am][bn] = floatx4{0.f, 0.f, 0.f, 0.f};

    // A staging: 128 rows x 32 k; thread -> (row = tid>>1, half = (tid&1)*16)
    const int arow = tid >> 1, ahalf = (tid & 1) * 16;
    const int gA = rowBase + arow;
    const float* aF = nullptr; const u16* aH = nullptr;
    if (ASRC == 0) {
        aF = (const float*)A1v + (long long)gA * K;
    } else if (ASRC == 1) {
        int b = gA / 3072, r = gA - b * 3072;   // 128-row tiles never straddle boundaries
        aF = (r < 1024) ? ((const float*)A1v + ((long long)b * 1024 + r) * K)
                        : ((const float*)A2v + ((long long)b * 2048 + (r - 1024)) * K);
    } else {
        aH = (const u16*)A1v + (long long)gA * K;
    }
    // B staging: 64 rows x 32 k; thread -> (row = tid>>2, col = (tid&3)*8)
    const int brow = tid >> 2, bcol = (tid & 3) * 8;
    const float* wrow = W + (long long)(colBase + brow) * K;

    for (int k0 = 0; k0 < K; k0 += 32) {
        u16x8 av0, av1;
        if (ASRC == 2) {
            av0 = *(const u16x8*)(aH + k0 + ahalf);
            av1 = *(const u16x8*)(aH + k0 + ahalf + 8);
        } else {
            floatx4 f0 = *(const floatx4*)(aF + k0 + ahalf);
            floatx4 f1 = *(const floatx4*)(aF + k0 + ahalf + 4);
            floatx4 f2 = *(const floatx4*)(aF + k0 + ahalf + 8);
            floatx4 f3 = *(const floatx4*)(aF + k0 + ahalf + 12);
            #pragma unroll
            for (int i = 0; i < 4; i++) {
                av0[i] = f2bf(f0[i]); av0[4 + i] = f2bf(f1[i]);
                av1[i] = f2bf(f2[i]); av1[4 + i] = f2bf(f3[i]);
            }
        }
        u16x8 wv;
        {
            floatx4 w0 = *(const floatx4*)(wrow + k0 + bcol);
            floatx4 w1 = *(const floatx4*)(wrow + k0 + bcol + 4);
            #pragma unroll
            for (int i = 0; i < 4; i++) { wv[i] = f2bf(w0[i]); wv[4 + i] = f2bf(w1[i]); }
        }
        *(u16x8*)&As[arow * 40 + ahalf]     = av0;
        *(u16x8*)&As[arow * 40 + ahalf + 8] = av1;
        *(u16x8*)&Bs[brow * 40 + bcol]      = wv;
        __syncthreads();

        u16x8 afr[4], bfr[2];
        #pragma unroll
        for (int am = 0; am < 4; am++)
            afr[am] = *(const u16x8*)&As[(wm + am * 16 + lane16) * 40 + quad * 8];
        #pragma unroll
        for (int bn = 0; bn < 2; bn++)
            bfr[bn] = *(const u16x8*)&Bs[(wn + bn * 16 + lane16) * 40 + quad * 8];
        #pragma unroll
        for (int am = 0; am < 4; am++)
            #pragma unroll
            for (int bn = 0; bn < 2; bn++)
                acc[am][bn] = __builtin_amdgcn_mfma_f32_16x16x32_bf16(
                    __builtin_bit_cast(bf16x8, afr[am]),
                    __builtin_bit_cast(bf16x8, bfr[bn]), acc[am][bn], 0, 0, 0);
        __syncthreads();
    }

    // C/D layout: col = lane16, row = quad*4 + r.
    #pragma unroll
    for (int am = 0; am < 4; am++)
        #pragma unroll
        for (int bn = 0; bn < 2; bn++)
            #pragma unroll
            for (int r = 0; r < 4; r++) {
                int row = rowBase + wm + am * 16 + quad * 4 + r;
                int col = colBase + wn + bn * 16 + lane16;
                float v = acc[am][bn][r] + bias[col];
                if (OUT_F32) ((float*)Cv)[(long long)row * N + col] = v;
                else         ((u16*)Cv)[(long long)row * N + col] = f2bf(v);
            }
}

// ---------------------------------------------------------------------------
// MFMA flash attention, pipelined (unchanged from R10 — first-launch verified).
// Block = (b,h,64 q rows); wave = 16 q rows. S^T = K@Q^T from prefetched K
// regs; softmax stats via 2 shuffles; P via wave-private LDS (in-order ds,
// wave_barrier); O^T = V^T@P^T with double-buffered Vt -> ONE block barrier
// per tile. Ctx may alias Q (Q consumed into regs first; regions disjoint).
// ---------------------------------------------------------------------------
__global__ __launch_bounds__(256) void attn_mfma(const u16* __restrict__ Q,
                                                 const u16* __restrict__ Kb,
                                                 const u16* __restrict__ Vb,
                                                 u16* __restrict__ Ctx) {
    __shared__ u16 Vt[2][64 * 80];     // 20 KB double-buffered V^T[d][key]
    __shared__ u16 Ps[4][16 * 80];     // 10 KB per-wave P[q][key]
    const int tid = threadIdx.x;
    const int wave = tid >> 6, lane = tid & 63;
    const int lane16 = lane & 15, quad = lane >> 4;
    const int qt = blockIdx.x & 15;
    const int h  = (blockIdx.x >> 4) & 15;
    const int b  = blockIdx.x >> 8;
    const int l0 = qt * 64;
    const int wq = wave * 16;
    const float scale = 0.125f;  // 1/sqrt(64)
    const int ntile = 3 * (qt + 1);

    bf16x8 qf[2];
    {
        const u16* qrow = Q + ((long long)(b * 1024 + l0 + wq + lane16)) * 1024 + h * 64;
        qf[0] = __builtin_bit_cast(bf16x8, *(const u16x8*)(qrow + quad * 8));
        qf[1] = __builtin_bit_cast(bf16x8, *(const u16x8*)(qrow + 32 + quad * 8));
    }

    const int skey = tid >> 2, sdb = (tid & 3) * 16;
    const long long bh = ((long long)b * 3072) * 1024 + h * 64;

    u16x8 kr[8], vr0, vr1;
    {
        long long o = bh;  // seg 0, t 0
        vr0 = *(const u16x8*)(Vb + o + (long long)skey * 1024 + sdb);
        vr1 = *(const u16x8*)(Vb + o + (long long)skey * 1024 + sdb + 8);
        #pragma unroll
        for (int c = 0; c < 2; c++)
            #pragma unroll
            for (int mi = 0; mi < 4; mi++)
                kr[c * 4 + mi] = *(const u16x8*)(Kb + o + (long long)(mi * 16 + lane16) * 1024 + c * 32 + quad * 8);
    }
    #pragma unroll
    for (int i = 0; i < 8; i++) {
        Vt[0][(sdb + i) * 80 + skey]     = vr0[i];
        Vt[0][(sdb + 8 + i) * 80 + skey] = vr1[i];
    }
    __syncthreads();

    float m_i = -1e30f, l_i = 0.f;
    floatx4 o_acc[4];
    #pragma unroll
    for (int mi = 0; mi < 4; mi++) o_acc[mi] = floatx4{0.f, 0.f, 0.f, 0.f};

    int seg = 0, t = 0;
    for (int idx = 0; idx < ntile; idx++) {
        const int cur = idx & 1;
        const bool haveNext = (idx + 1) < ntile;
        int nseg = seg, nt_ = t + 1;
        if (nt_ > qt) { nt_ = 0; nseg = seg + 1; }

        u16x8 nkr[8], nvr0, nvr1;
        if (haveNext) {
            long long o = bh + ((long long)(nseg * 1024 + nt_ * 64)) * 1024;
            nvr0 = *(const u16x8*)(Vb + o + (long long)skey * 1024 + sdb);
            nvr1 = *(const u16x8*)(Vb + o + (long long)skey * 1024 + sdb + 8);
            #pragma unroll
            for (int c = 0; c < 2; c++)
                #pragma unroll
                for (int mi = 0; mi < 4; mi++)
                    nkr[c * 4 + mi] = *(const u16x8*)(Kb + o + (long long)(mi * 16 + lane16) * 1024 + c * 32 + quad * 8);
        }

        floatx4 sacc[4];
        #pragma unroll
        for (int mi = 0; mi < 4; mi++) sacc[mi] = floatx4{0.f, 0.f, 0.f, 0.f};
        #pragma unroll
        for (int c = 0; c < 2; c++)
            #pragma unroll
            for (int mi = 0; mi < 4; mi++)
                sacc[mi] = __builtin_amdgcn_mfma_f32_16x16x32_bf16(
                    __builtin_bit_cast(bf16x8, kr[c * 4 + mi]), qf[c], sacc[mi], 0, 0, 0);

        const bool diag = (t == qt);
        const int qloc = wq + lane16;
        float tmax = -1e30f;
        #pragma unroll
        for (int mi = 0; mi < 4; mi++)
            #pragma unroll
            for (int r = 0; r < 4; r++) {
                float s = sacc[mi][r] * scale;
                if (diag && (mi * 16 + quad * 4 + r) > qloc) s = -1e30f;
                sacc[mi][r] = s;
                tmax = fmaxf(tmax, s);
            }
        tmax = fmaxf(tmax, __shfl_xor(tmax, 16));
        tmax = fmaxf(tmax, __shfl_xor(tmax, 32));
        float m_new = fmaxf(m_i, tmax);
        float alpha = __expf(m_i - m_new);
        float psum = 0.f;
        #pragma unroll
        for (int mi = 0; mi < 4; mi++)
            #pragma unroll
            for (int r = 0; r < 4; r++) {
                float p = __expf(sacc[mi][r] - m_new);
                psum += p;
                Ps[wave][lane16 * 80 + mi * 16 + quad * 4 + r] = f2bf(p);
            }
        psum += __shfl_xor(psum, 16);
        psum += __shfl_xor(psum, 32);
        m_i = m_new;
        l_i = l_i * alpha + psum;
        #pragma unroll
        for (int mi = 0; mi < 4; mi++)
            #pragma unroll
            for (int r = 0; r < 4; r++) o_acc[mi][r] *= alpha;

        __builtin_amdgcn_wave_barrier();  // wave-private Ps: in-order ds suffices

        #pragma unroll
        for (int c = 0; c < 2; c++) {
            bf16x8 pf = __builtin_bit_cast(bf16x8,
                *(const u16x8*)&Ps[wave][lane16 * 80 + c * 32 + quad * 8]);
            #pragma unroll
            for (int mi = 0; mi < 4; mi++) {
                bf16x8 vf = __builtin_bit_cast(bf16x8,
                    *(const u16x8*)&Vt[cur][(mi * 16 + lane16) * 80 + c * 32 + quad * 8]);
                o_acc[mi] = __builtin_amdgcn_mfma_f32_16x16x32_bf16(vf, pf, o_acc[mi], 0, 0, 0);
            }
        }

        if (haveNext) {
            #pragma unroll
            for (int i = 0; i < 8; i++) {
                Vt[cur ^ 1][(sdb + i) * 80 + skey]     = nvr0[i];
                Vt[cur ^ 1][(sdb + 8 + i) * 80 + skey] = nvr1[i];
            }
            #pragma unroll
            for (int i = 0; i < 8; i++) kr[i] = nkr[i];
            __syncthreads();  // the ONLY block barrier per tile
        }
        seg = nseg; t = nt_;
    }

    const float inv_l = 1.0f / l_i;
    long long crow = ((long long)(b * 1024 + l0 + wq + lane16)) * 1024 + h * 64;
    #pragma unroll
    for (int mi = 0; mi < 4; mi++)
        #pragma unroll
        for (int r = 0; r < 4; r++)
            Ctx[crow + mi * 16 + quad * 4 + r] = f2bf(o_acc[mi][r] * inv_l);
}

// ---------------------------------------------------------------------------
// residual + LayerNorm + mask. One block per row. fp32 in, fp32 out.
// ---------------------------------------------------------------------------
__global__ __launch_bounds__(256) void ln_kernel(const float* __restrict__ AO,
                                                 const float* __restrict__ HQ,
                                                 const float* __restrict__ g,
                                                 const float* __restrict__ bb,
                                                 const float* __restrict__ mask,
                                                 float* __restrict__ Out) {
    const int row = blockIdx.x;
    const int t = threadIdx.x;
    const int base = row * 1024 + t * 4;
    floatx4 a  = *(const floatx4*)&AO[base];
    floatx4 hq = *(const floatx4*)&HQ[base];
    float x[4];
    #pragma unroll
    for (int i = 0; i < 4; i++) x[i] = a[i] + hq[i];
    float s = x[0] + x[1] + x[2] + x[3];
    float ss = x[0]*x[0] + x[1]*x[1] + x[2]*x[2] + x[3]*x[3];
    #pragma unroll
    for (int off = 32; off >= 1; off >>= 1) { s += __shfl_xor(s, off); ss += __shfl_xor(ss, off); }
    __shared__ float smem[8];
    int wave = t >> 6, lane = t & 63;
    if (lane == 0) { smem[wave] = s; smem[4 + wave] = ss; }
    __syncthreads();
    s  = smem[0] + smem[1] + smem[2] + smem[3];
    ss = smem[4] + smem[5] + smem[6] + smem[7];
    float mu  = s * (1.f / 1024.f);
    float var = ss * (1.f / 1024.f) - mu * mu;
    float rs  = rsqrtf(var + 1e-5f);
    float mv  = mask[row];
    floatx4 g4 = *(const floatx4*)&g[t * 4];
    floatx4 b4 = *(const floatx4*)&bb[t * 4];
    floatx4 y4;
    #pragma unroll
    for (int i = 0; i < 4; i++) y4[i] = ((x[i] - mu) * rs * g4[i] + b4[i]) * mv;
    *(floatx4*)&Out[base] = y4;
}

// ---------------------------------------------------------------------------
// Workspace: 28 MB total (PROVEN safe in R8/R9; 36 MB broke replay -> OOB).
//   ws+0      q_b (4 MB bf16) -> reused in-place as ctx by attn_mfma
//   ws+4 MB   k_b (12 MB bf16) -> reused as ao (fp32 8 MB) after attention
//   ws+16 MB  v_b (12 MB bf16)
// ---------------------------------------------------------------------------
extern "C" void kernel_launch(void* const* d_in, const int* in_sizes, int n_in,
                              void* d_out, int out_size, void* d_ws, size_t ws_size,
                              hipStream_t stream) {
    (void)in_sizes; (void)n_in; (void)out_size; (void)ws_size;
    const float* h_q   = (const float*)d_in[0];
    const float* h_kv1 = (const float*)d_in[1];
    const float* h_kv2 = (const float*)d_in[2];
    const float* maskp = (const float*)d_in[3];
    const float* win   = (const float*)d_in[4];
    const float* binp  = (const float*)d_in[5];
    const float* wout  = (const float*)d_in[6];
    const float* bout  = (const float*)d_in[7];
    const float* ln_g  = (const float*)d_in[8];
    const float* ln_b  = (const float*)d_in[9];
    float* outp = (float*)d_out;

    char* ws = (char*)d_ws;
    const size_t MB = 1024 * 1024;
    u16*   q_b   = (u16*)(ws);             // 4 MB; becomes ctx in-place
    u16*   k_b   = (u16*)(ws + 4 * MB);    // 12 MB; dead after attn
    u16*   v_b   = (u16*)(ws + 16 * MB);   // 12 MB
    u16*   ctx_b = q_b;                    // alias (safe: see attn_mfma note)
    float* ao    = (float*)(ws + 4 * MB);  // overwrites k_b after attn (8 MB)

    gemm128<0, false><<<dim3(16, 16), 256, 0, stream>>>(h_q,   nullptr, win,                   binp,        (void*)q_b);
    gemm128<1, false><<<dim3(16, 48), 256, 0, stream>>>(h_kv1, h_kv2,   win + 1024 * 1024,     binp + 1024, (void*)k_b);
    gemm128<1, false><<<dim3(16, 48), 256, 0, stream>>>(h_kv1, h_kv2,   win + 2 * 1024 * 1024, binp + 2048, (void*)v_b);
    attn_mfma<<<512, 256, 0, stream>>>(q_b, k_b, v_b, ctx_b);
    gemm128<2, true><<<dim3(16, 16), 256, 0, stream>>>(ctx_b, nullptr, wout, bout, (void*)ao);
    ln_kernel<<<2048, 256, 0, stream>>>(ao, h_q, ln_g, ln_b, maskp, outp);
}

// Round 12
// 329.731 us; speedup vs baseline: 6.3356x; 1.0484x over previous
//
#include <hip/hip_runtime.h>
#include <stdint.h>

typedef unsigned short u16;
typedef __bf16 bf16x8 __attribute__((ext_vector_type(8)));
typedef float floatx4 __attribute__((ext_vector_type(4)));
typedef u16 u16x8 __attribute__((ext_vector_type(8)));

__device__ __forceinline__ float bf2f(u16 u) {
    union { unsigned int i; float f; } v; v.i = ((unsigned int)u) << 16; return v.f;
}
// HW f32->bf16 (RTNE): compiler emits v_cvt_pk_bf16_f32 on gfx950.
__device__ __forceinline__ u16 f2bf(float f) {
    __bf16 h = (__bf16)f;
    return __builtin_bit_cast(u16, h);
}

// ---------------------------------------------------------------------------
// MFMA GEMM, 128x64 tile: C[M,1024] = A[M,1024] @ W^T + bias.
//   W fp32 (HW-converted to bf16 during LDS staging). A: 0 = fp32 direct,
//   1 = fp32 concat kv1|kv2, 2 = bf16. BK=32, 4 waves in 2x2 (64x32 each).
// ---------------------------------------------------------------------------
template <int ASRC, bool OUT_F32>
__global__ __launch_bounds__(256) void gemm128(const void* __restrict__ A1v,
                                               const void* __restrict__ A2v,
                                               const float* __restrict__ W,
                                               const float* __restrict__ bias,
                                               void* __restrict__ Cv) {
    const int K = 1024, N = 1024;
    __shared__ u16 As[128 * 40];
    __shared__ u16 Bs[64 * 40];
    const int tid = threadIdx.x;
    const int wave = tid >> 6, lane = tid & 63;
    const int lane16 = lane & 15, quad = lane >> 4;
    const int rowBase = blockIdx.y * 128;
    const int colBase = blockIdx.x * 64;
    const int wm = (wave >> 1) * 64, wn = (wave & 1) * 32;

    floatx4 acc[4][2];
    #pragma unroll
    for (int am = 0; am < 4; am++)
        #pragma unroll
        for (int bn = 0; bn < 2; bn++) acc[am][bn] = floatx4{0.f, 0.f, 0.f, 0.f};

    const int arow = tid >> 1, ahalf = (tid & 1) * 16;
    const int gA = rowBase + arow;
    const float* aF = nullptr; const u16* aH = nullptr;
    if (ASRC == 0) {
        aF = (const float*)A1v + (long long)gA * K;
    } else if (ASRC == 1) {
        int b = gA / 3072, r = gA - b * 3072;   // 128-row tiles never straddle boundaries
        aF = (r < 1024) ? ((const float*)A1v + ((long long)b * 1024 + r) * K)
                        : ((const float*)A2v + ((long long)b * 2048 + (r - 1024)) * K);
    } else {
        aH = (const u16*)A1v + (long long)gA * K;
    }
    const int brow = tid >> 2, bcol = (tid & 3) * 8;
    const float* wrow = W + (long long)(colBase + brow) * K;

    for (int k0 = 0; k0 < K; k0 += 32) {
        u16x8 av0, av1;
        if (ASRC == 2) {
            av0 = *(const u16x8*)(aH + k0 + ahalf);
            av1 = *(const u16x8*)(aH + k0 + ahalf + 8);
        } else {
            floatx4 f0 = *(const floatx4*)(aF + k0 + ahalf);
            floatx4 f1 = *(const floatx4*)(aF + k0 + ahalf + 4);
            floatx4 f2 = *(const floatx4*)(aF + k0 + ahalf + 8);
            floatx4 f3 = *(const floatx4*)(aF + k0 + ahalf + 12);
            #pragma unroll
            for (int i = 0; i < 4; i++) {
                av0[i] = f2bf(f0[i]); av0[4 + i] = f2bf(f1[i]);
                av1[i] = f2bf(f2[i]); av1[4 + i] = f2bf(f3[i]);
            }
        }
        u16x8 wv;
        {
            floatx4 w0 = *(const floatx4*)(wrow + k0 + bcol);
            floatx4 w1 = *(const floatx4*)(wrow + k0 + bcol + 4);
            #pragma unroll
            for (int i = 0; i < 4; i++) { wv[i] = f2bf(w0[i]); wv[4 + i] = f2bf(w1[i]); }
        }
        *(u16x8*)&As[arow * 40 + ahalf]     = av0;
        *(u16x8*)&As[arow * 40 + ahalf + 8] = av1;
        *(u16x8*)&Bs[brow * 40 + bcol]      = wv;
        __syncthreads();

        u16x8 afr[4], bfr[2];
        #pragma unroll
        for (int am = 0; am < 4; am++)
            afr[am] = *(const u16x8*)&As[(wm + am * 16 + lane16) * 40 + quad * 8];
        #pragma unroll
        for (int bn = 0; bn < 2; bn++)
            bfr[bn] = *(const u16x8*)&Bs[(wn + bn * 16 + lane16) * 40 + quad * 8];
        #pragma unroll
        for (int am = 0; am < 4; am++)
            #pragma unroll
            for (int bn = 0; bn < 2; bn++)
                acc[am][bn] = __builtin_amdgcn_mfma_f32_16x16x32_bf16(
                    __builtin_bit_cast(bf16x8, afr[am]),
                    __builtin_bit_cast(bf16x8, bfr[bn]), acc[am][bn], 0, 0, 0);
        __syncthreads();
    }

    // C/D layout: col = lane16, row = quad*4 + r.
    #pragma unroll
    for (int am = 0; am < 4; am++)
        #pragma unroll
        for (int bn = 0; bn < 2; bn++)
            #pragma unroll
            for (int r = 0; r < 4; r++) {
                int row = rowBase + wm + am * 16 + quad * 4 + r;
                int col = colBase + wn + bn * 16 + lane16;
                float v = acc[am][bn][r] + bias[col];
                if (OUT_F32) ((float*)Cv)[(long long)row * N + col] = v;
                else         ((u16*)Cv)[(long long)row * N + col] = f2bf(v);
            }
}

// ---------------------------------------------------------------------------
// MFMA flash attention, pipelined + load-balanced.
// qt remap: for b=1 (blockIdx bit 8), qt = 15 - (idx&15). Under round-robin
// dispatch, blocks i and i+256 share a CU; their tile counts then sum to a
// constant 51 -- balancing the causal-length skew. Pure permutation of
// (b,h,qt) -> correctness unaffected by the actual dispatch mapping.
// ---------------------------------------------------------------------------
__global__ __launch_bounds__(256) void attn_mfma(const u16* __restrict__ Q,
                                                 const u16* __restrict__ Kb,
                                                 const u16* __restrict__ Vb,
                                                 u16* __restrict__ Ctx) {
    __shared__ u16 Vt[2][64 * 80];     // 20 KB double-buffered V^T[d][key]
    __shared__ u16 Ps[4][16 * 80];     // 10 KB per-wave P[q][key]
    const int tid = threadIdx.x;
    const int wave = tid >> 6, lane = tid & 63;
    const int lane16 = lane & 15, quad = lane >> 4;
    const int idx_ = blockIdx.x;
    const int qhat = idx_ & 15;
    const int h  = (idx_ >> 4) & 15;
    const int b  = idx_ >> 8;
    const int qt = b ? (15 - qhat) : qhat;   // load-balance remap
    const int l0 = qt * 64;
    const int wq = wave * 16;
    const float scale = 0.125f;  // 1/sqrt(64)
    const int ntile = 3 * (qt + 1);

    bf16x8 qf[2];
    {
        const u16* qrow = Q + ((long long)(b * 1024 + l0 + wq + lane16)) * 1024 + h * 64;
        qf[0] = __builtin_bit_cast(bf16x8, *(const u16x8*)(qrow + quad * 8));
        qf[1] = __builtin_bit_cast(bf16x8, *(const u16x8*)(qrow + 32 + quad * 8));
    }

    const int skey = tid >> 2, sdb = (tid & 3) * 16;
    const long long bh = ((long long)b * 3072) * 1024 + h * 64;

    u16x8 kr[8], vr0, vr1;
    {
        long long o = bh;  // seg 0, t 0
        vr0 = *(const u16x8*)(Vb + o + (long long)skey * 1024 + sdb);
        vr1 = *(const u16x8*)(Vb + o + (long long)skey * 1024 + sdb + 8);
        #pragma unroll
        for (int c = 0; c < 2; c++)
            #pragma unroll
            for (int mi = 0; mi < 4; mi++)
                kr[c * 4 + mi] = *(const u16x8*)(Kb + o + (long long)(mi * 16 + lane16) * 1024 + c * 32 + quad * 8);
    }
    #pragma unroll
    for (int i = 0; i < 8; i++) {
        Vt[0][(sdb + i) * 80 + skey]     = vr0[i];
        Vt[0][(sdb + 8 + i) * 80 + skey] = vr1[i];
    }
    __syncthreads();

    float m_i = -1e30f, l_i = 0.f;
    floatx4 o_acc[4];
    #pragma unroll
    for (int mi = 0; mi < 4; mi++) o_acc[mi] = floatx4{0.f, 0.f, 0.f, 0.f};

    int seg = 0, t = 0;
    for (int idx = 0; idx < ntile; idx++) {
        const int cur = idx & 1;
        const bool haveNext = (idx + 1) < ntile;
        int nseg = seg, nt_ = t + 1;
        if (nt_ > qt) { nt_ = 0; nseg = seg + 1; }

        u16x8 nkr[8], nvr0, nvr1;
        if (haveNext) {
            long long o = bh + ((long long)(nseg * 1024 + nt_ * 64)) * 1024;
            nvr0 = *(const u16x8*)(Vb + o + (long long)skey * 1024 + sdb);
            nvr1 = *(const u16x8*)(Vb + o + (long long)skey * 1024 + sdb + 8);
            #pragma unroll
            for (int c = 0; c < 2; c++)
                #pragma unroll
                for (int mi = 0; mi < 4; mi++)
                    nkr[c * 4 + mi] = *(const u16x8*)(Kb + o + (long long)(mi * 16 + lane16) * 1024 + c * 32 + quad * 8);
        }

        floatx4 sacc[4];
        #pragma unroll
        for (int mi = 0; mi < 4; mi++) sacc[mi] = floatx4{0.f, 0.f, 0.f, 0.f};
        #pragma unroll
        for (int c = 0; c < 2; c++)
            #pragma unroll
            for (int mi = 0; mi < 4; mi++)
                sacc[mi] = __builtin_amdgcn_mfma_f32_16x16x32_bf16(
                    __builtin_bit_cast(bf16x8, kr[c * 4 + mi]), qf[c], sacc[mi], 0, 0, 0);

        const bool diag = (t == qt);
        const int qloc = wq + lane16;
        float tmax = -1e30f;
        #pragma unroll
        for (int mi = 0; mi < 4; mi++)
            #pragma unroll
            for (int r = 0; r < 4; r++) {
                float s = sacc[mi][r] * scale;
                if (diag && (mi * 16 + quad * 4 + r) > qloc) s = -1e30f;
                sacc[mi][r] = s;
                tmax = fmaxf(tmax, s);
            }
        tmax = fmaxf(tmax, __shfl_xor(tmax, 16));
        tmax = fmaxf(tmax, __shfl_xor(tmax, 32));
        float m_new = fmaxf(m_i, tmax);
        float alpha = __expf(m_i - m_new);
        float psum = 0.f;
        #pragma unroll
        for (int mi = 0; mi < 4; mi++)
            #pragma unroll
            for (int r = 0; r < 4; r++) {
                float p = __expf(sacc[mi][r] - m_new);
                psum += p;
                Ps[wave][lane16 * 80 + mi * 16 + quad * 4 + r] = f2bf(p);
            }
        psum += __shfl_xor(psum, 16);
        psum += __shfl_xor(psum, 32);
        m_i = m_new;
        l_i = l_i * alpha + psum;
        #pragma unroll
        for (int mi = 0; mi < 4; mi++)
            #pragma unroll
            for (int r = 0; r < 4; r++) o_acc[mi][r] *= alpha;

        __builtin_amdgcn_wave_barrier();  // wave-private Ps: in-order ds suffices

        #pragma unroll
        for (int c = 0; c < 2; c++) {
            bf16x8 pf = __builtin_bit_cast(bf16x8,
                *(const u16x8*)&Ps[wave][lane16 * 80 + c * 32 + quad * 8]);
            #pragma unroll
            for (int mi = 0; mi < 4; mi++) {
                bf16x8 vf = __builtin_bit_cast(bf16x8,
                    *(const u16x8*)&Vt[cur][(mi * 16 + lane16) * 80 + c * 32 + quad * 8]);
                o_acc[mi] = __builtin_amdgcn_mfma_f32_16x16x32_bf16(vf, pf, o_acc[mi], 0, 0, 0);
            }
        }

        if (haveNext) {
            #pragma unroll
            for (int i = 0; i < 8; i++) {
                Vt[cur ^ 1][(sdb + i) * 80 + skey]     = nvr0[i];
                Vt[cur ^ 1][(sdb + 8 + i) * 80 + skey] = nvr1[i];
            }
            #pragma unroll
            for (int i = 0; i < 8; i++) kr[i] = nkr[i];
            __syncthreads();  // the ONLY block barrier per tile
        }
        seg = nseg; t = nt_;
    }

    const float inv_l = 1.0f / l_i;
    long long crow = ((long long)(b * 1024 + l0 + wq + lane16)) * 1024 + h * 64;
    #pragma unroll
    for (int mi = 0; mi < 4; mi++)
        #pragma unroll
        for (int r = 0; r < 4; r++)
            Ctx[crow + mi * 16 + quad * 4 + r] = f2bf(o_acc[mi][r] * inv_l);
}

// ---------------------------------------------------------------------------
// residual + LayerNorm + mask. One block per row. fp32 in, fp32 out.
// ---------------------------------------------------------------------------
__global__ __launch_bounds__(256) void ln_kernel(const float* __restrict__ AO,
                                                 const float* __restrict__ HQ,
                                                 const float* __restrict__ g,
                                                 const float* __restrict__ bb,
                                                 const float* __restrict__ mask,
                                                 float* __restrict__ Out) {
    const int row = blockIdx.x;
    const int t = threadIdx.x;
    const int base = row * 1024 + t * 4;
    floatx4 a  = *(const floatx4*)&AO[base];
    floatx4 hq = *(const floatx4*)&HQ[base];
    float x[4];
    #pragma unroll
    for (int i = 0; i < 4; i++) x[i] = a[i] + hq[i];
    float s = x[0] + x[1] + x[2] + x[3];
    float ss = x[0]*x[0] + x[1]*x[1] + x[2]*x[2] + x[3]*x[3];
    #pragma unroll
    for (int off = 32; off >= 1; off >>= 1) { s += __shfl_xor(s, off); ss += __shfl_xor(ss, off); }
    __shared__ float smem[8];
    int wave = t >> 6, lane = t & 63;
    if (lane == 0) { smem[wave] = s; smem[4 + wave] = ss; }
    __syncthreads();
    s  = smem[0] + smem[1] + smem[2] + smem[3];
    ss = smem[4] + smem[5] + smem[6] + smem[7];
    float mu  = s * (1.f / 1024.f);
    float var = ss * (1.f / 1024.f) - mu * mu;
    float rs  = rsqrtf(var + 1e-5f);
    float mv  = mask[row];
    floatx4 g4 = *(const floatx4*)&g[t * 4];
    floatx4 b4 = *(const floatx4*)&bb[t * 4];
    floatx4 y4;
    #pragma unroll
    for (int i = 0; i < 4; i++) y4[i] = ((x[i] - mu) * rs * g4[i] + b4[i]) * mv;
    *(floatx4*)&Out[base] = y4;
}

// ---------------------------------------------------------------------------
// Workspace: 28 MB total (proven safe; 36 MB broke replay -> OOB).
//   ws+0      q_b (4 MB bf16) -> reused in-place as ctx by attn_mfma
//   ws+4 MB   k_b (12 MB bf16) -> reused as ao (fp32 8 MB) after attention
//   ws+16 MB  v_b (12 MB bf16)
// ---------------------------------------------------------------------------
extern "C" void kernel_launch(void* const* d_in, const int* in_sizes, int n_in,
                              void* d_out, int out_size, void* d_ws, size_t ws_size,
                              hipStream_t stream) {
    (void)in_sizes; (void)n_in; (void)out_size; (void)ws_size;
    const float* h_q   = (const float*)d_in[0];
    const float* h_kv1 = (const float*)d_in[1];
    const float* h_kv2 = (const float*)d_in[2];
    const float* maskp = (const float*)d_in[3];
    const float* win   = (const float*)d_in[4];
    const float* binp  = (const float*)d_in[5];
    const float* wout  = (const float*)d_in[6];
    const float* bout  = (const float*)d_in[7];
    const float* ln_g  = (const float*)d_in[8];
    const float* ln_b  = (const float*)d_in[9];
    float* outp = (float*)d_out;

    char* ws = (char*)d_ws;
    const size_t MB = 1024 * 1024;
    u16*   q_b   = (u16*)(ws);             // 4 MB; becomes ctx in-place
    u16*   k_b   = (u16*)(ws + 4 * MB);    // 12 MB; dead after attn
    u16*   v_b   = (u16*)(ws + 16 * MB);   // 12 MB
    u16*   ctx_b = q_b;                    // alias (safe: see attn_mfma note)
    float* ao    = (float*)(ws + 4 * MB);  // overwrites k_b after attn (8 MB)

    gemm128<0, false><<<dim3(16, 16), 256, 0, stream>>>(h_q,   nullptr, win,                   binp,        (void*)q_b);
    gemm128<1, false><<<dim3(16, 48), 256, 0, stream>>>(h_kv1, h_kv2,   win + 1024 * 1024,     binp + 1024, (void*)k_b);
    gemm128<1, false><<<dim3(16, 48), 256, 0, stream>>>(h_kv1, h_kv2,   win + 2 * 1024 * 1024, binp + 2048, (void*)v_b);
    attn_mfma<<<512, 256, 0, stream>>>(q_b, k_b, v_b, ctx_b);
    gemm128<2, true><<<dim3(16, 16), 256, 0, stream>>>(ctx_b, nullptr, wout, bout, (void*)ao);
    ln_kernel<<<2048, 256, 0, stream>>>(ao, h_q, ln_g, ln_b, maskp, outp);
}

// Round 13
// 305.758 us; speedup vs baseline: 6.8324x; 1.0784x over previous
//
#include <hip/hip_runtime.h>
#include <stdint.h>

typedef unsigned short u16;
typedef __bf16 bf16x8 __attribute__((ext_vector_type(8)));
typedef float floatx4 __attribute__((ext_vector_type(4)));
typedef u16 u16x8 __attribute__((ext_vector_type(8)));

__device__ __forceinline__ float bf2f(u16 u) {
    union { unsigned int i; float f; } v; v.i = ((unsigned int)u) << 16; return v.f;
}
__device__ __forceinline__ u16 f2bf(float f) {
    __bf16 h = (__bf16)f;
    return __builtin_bit_cast(u16, h);
}

// ---------------------------------------------------------------------------
// Fused K+V projection GEMM, 128x128 tile, reg-prefetch pipeline.
// C[6144,2048] = concat(kv1,kv2)[6144,1024] @ W[2048,1024]^T + bias.
// cols 0..1023 -> Kout, 1024..2047 -> Vout (Vout = Kout + 6144*1024).
// ---------------------------------------------------------------------------
__global__ __launch_bounds__(256) void gemm_kv(const float* __restrict__ kv1,
                                               const float* __restrict__ kv2,
                                               const float* __restrict__ W,
                                               const float* __restrict__ bias,
                                               u16* __restrict__ Kout) {
    const int K = 1024;
    __shared__ u16 As[128 * 40];
    __shared__ u16 Bs[128 * 40];
    const int tid = threadIdx.x;
    const int wave = tid >> 6, lane = tid & 63;
    const int lane16 = lane & 15, quad = lane >> 4;
    const int rowBase = blockIdx.y * 128;
    const int colBase = blockIdx.x * 128;
    const int wm = (wave >> 1) * 64, wn = (wave & 1) * 64;

    floatx4 acc[4][4];
    #pragma unroll
    for (int am = 0; am < 4; am++)
        #pragma unroll
        for (int bn = 0; bn < 4; bn++) acc[am][bn] = floatx4{0.f, 0.f, 0.f, 0.f};

    // staging: row = tid>>1 (0..127), 16 k-elems at (tid&1)*16
    const int srow = tid >> 1, shalf = (tid & 1) * 16;
    const int gA = rowBase + srow;
    int bb_ = gA / 3072, r_ = gA - bb_ * 3072;   // tiles never straddle (3072%128==0, 1024%128==0)
    const float* aF = (r_ < 1024) ? (kv1 + ((long long)bb_ * 1024 + r_) * K)
                                  : (kv2 + ((long long)bb_ * 2048 + (r_ - 1024)) * K);
    const float* wF = W + (long long)(colBase + srow) * K;

    floatx4 aR[4], bR[4];
    #pragma unroll
    for (int i = 0; i < 4; i++) {
        aR[i] = *(const floatx4*)(aF + shalf + i * 4);
        bR[i] = *(const floatx4*)(wF + shalf + i * 4);
    }

    for (int k0 = 0; k0 < K; k0 += 32) {
        u16x8 av0, av1, bv0, bv1;
        #pragma unroll
        for (int i = 0; i < 4; i++) {
            av0[i] = f2bf(aR[0][i]); av0[4 + i] = f2bf(aR[1][i]);
            av1[i] = f2bf(aR[2][i]); av1[4 + i] = f2bf(aR[3][i]);
            bv0[i] = f2bf(bR[0][i]); bv0[4 + i] = f2bf(bR[1][i]);
            bv1[i] = f2bf(bR[2][i]); bv1[4 + i] = f2bf(bR[3][i]);
        }
        *(u16x8*)&As[srow * 40 + shalf]     = av0;
        *(u16x8*)&As[srow * 40 + shalf + 8] = av1;
        *(u16x8*)&Bs[srow * 40 + shalf]     = bv0;
        *(u16x8*)&Bs[srow * 40 + shalf + 8] = bv1;
        __syncthreads();

        if (k0 + 32 < K) {   // prefetch next K-step (latency hides behind MFMAs)
            #pragma unroll
            for (int i = 0; i < 4; i++) {
                aR[i] = *(const floatx4*)(aF + k0 + 32 + shalf + i * 4);
                bR[i] = *(const floatx4*)(wF + k0 + 32 + shalf + i * 4);
            }
        }

        u16x8 afr[4], bfr[4];
        #pragma unroll
        for (int am = 0; am < 4; am++)
            afr[am] = *(const u16x8*)&As[(wm + am * 16 + lane16) * 40 + quad * 8];
        #pragma unroll
        for (int bn = 0; bn < 4; bn++)
            bfr[bn] = *(const u16x8*)&Bs[(wn + bn * 16 + lane16) * 40 + quad * 8];
        #pragma unroll
        for (int am = 0; am < 4; am++)
            #pragma unroll
            for (int bn = 0; bn < 4; bn++)
                acc[am][bn] = __builtin_amdgcn_mfma_f32_16x16x32_bf16(
                    __builtin_bit_cast(bf16x8, afr[am]),
                    __builtin_bit_cast(bf16x8, bfr[bn]), acc[am][bn], 0, 0, 0);
        __syncthreads();
    }

    // C/D: col = lane16, row = quad*4 + r. Split K|V at col 1024.
    #pragma unroll
    for (int am = 0; am < 4; am++)
        #pragma unroll
        for (int bn = 0; bn < 4; bn++)
            #pragma unroll
            for (int r = 0; r < 4; r++) {
                int row = rowBase + wm + am * 16 + quad * 4 + r;
                int col = colBase + wn + bn * 16 + lane16;
                float v = acc[am][bn][r] + bias[col];
                long long off = (col < 1024)
                    ? ((long long)row * 1024 + col)
                    : ((long long)6144 * 1024 + (long long)row * 1024 + (col - 1024));
                Kout[off] = f2bf(v);
            }
}

// ---------------------------------------------------------------------------
// MFMA GEMM, 128x64 tile, reg-prefetch pipeline.
//   ASRC 0: A fp32 direct. ASRC 2: A bf16 direct. W fp32 (cvt in staging).
// ---------------------------------------------------------------------------
template <int ASRC, bool OUT_F32>
__global__ __launch_bounds__(256) void gemm128(const void* __restrict__ A1v,
                                               const float* __restrict__ W,
                                               const float* __restrict__ bias,
                                               void* __restrict__ Cv) {
    const int K = 1024, N = 1024;
    __shared__ u16 As[128 * 40];
    __shared__ u16 Bs[64 * 40];
    const int tid = threadIdx.x;
    const int wave = tid >> 6, lane = tid & 63;
    const int lane16 = lane & 15, quad = lane >> 4;
    const int rowBase = blockIdx.y * 128;
    const int colBase = blockIdx.x * 64;
    const int wm = (wave >> 1) * 64, wn = (wave & 1) * 32;

    floatx4 acc[4][2];
    #pragma unroll
    for (int am = 0; am < 4; am++)
        #pragma unroll
        for (int bn = 0; bn < 2; bn++) acc[am][bn] = floatx4{0.f, 0.f, 0.f, 0.f};

    const int arow = tid >> 1, ahalf = (tid & 1) * 16;
    const float* aF = nullptr; const u16* aH = nullptr;
    if (ASRC == 0) aF = (const float*)A1v + (long long)(rowBase + arow) * K;
    else           aH = (const u16*)A1v + (long long)(rowBase + arow) * K;
    const int brow = tid >> 2, bcol = (tid & 3) * 8;
    const float* wF = W + (long long)(colBase + brow) * K;

    floatx4 aRf[4]; u16x8 aRh[2]; floatx4 bR[2];
    if (ASRC == 0) {
        #pragma unroll
        for (int i = 0; i < 4; i++) aRf[i] = *(const floatx4*)(aF + ahalf + i * 4);
    } else {
        aRh[0] = *(const u16x8*)(aH + ahalf);
        aRh[1] = *(const u16x8*)(aH + ahalf + 8);
    }
    bR[0] = *(const floatx4*)(wF + bcol);
    bR[1] = *(const floatx4*)(wF + bcol + 4);

    for (int k0 = 0; k0 < K; k0 += 32) {
        u16x8 av0, av1, wv;
        if (ASRC == 0) {
            #pragma unroll
            for (int i = 0; i < 4; i++) {
                av0[i] = f2bf(aRf[0][i]); av0[4 + i] = f2bf(aRf[1][i]);
                av1[i] = f2bf(aRf[2][i]); av1[4 + i] = f2bf(aRf[3][i]);
            }
        } else { av0 = aRh[0]; av1 = aRh[1]; }
        #pragma unroll
        for (int i = 0; i < 4; i++) { wv[i] = f2bf(bR[0][i]); wv[4 + i] = f2bf(bR[1][i]); }
        *(u16x8*)&As[arow * 40 + ahalf]     = av0;
        *(u16x8*)&As[arow * 40 + ahalf + 8] = av1;
        *(u16x8*)&Bs[brow * 40 + bcol]      = wv;
        __syncthreads();

        if (k0 + 32 < K) {
            if (ASRC == 0) {
                #pragma unroll
                for (int i = 0; i < 4; i++) aRf[i] = *(const floatx4*)(aF + k0 + 32 + ahalf + i * 4);
            } else {
                aRh[0] = *(const u16x8*)(aH + k0 + 32 + ahalf);
                aRh[1] = *(const u16x8*)(aH + k0 + 32 + ahalf + 8);
            }
            bR[0] = *(const floatx4*)(wF + k0 + 32 + bcol);
            bR[1] = *(const floatx4*)(wF + k0 + 32 + bcol + 4);
        }

        u16x8 afr[4], bfr[2];
        #pragma unroll
        for (int am = 0; am < 4; am++)
            afr[am] = *(const u16x8*)&As[(wm + am * 16 + lane16) * 40 + quad * 8];
        #pragma unroll
        for (int bn = 0; bn < 2; bn++)
            bfr[bn] = *(const u16x8*)&Bs[(wn + bn * 16 + lane16) * 40 + quad * 8];
        #pragma unroll
        for (int am = 0; am < 4; am++)
            #pragma unroll
            for (int bn = 0; bn < 2; bn++)
                acc[am][bn] = __builtin_amdgcn_mfma_f32_16x16x32_bf16(
                    __builtin_bit_cast(bf16x8, afr[am]),
                    __builtin_bit_cast(bf16x8, bfr[bn]), acc[am][bn], 0, 0, 0);
        __syncthreads();
    }

    #pragma unroll
    for (int am = 0; am < 4; am++)
        #pragma unroll
        for (int bn = 0; bn < 2; bn++)
            #pragma unroll
            for (int r = 0; r < 4; r++) {
                int row = rowBase + wm + am * 16 + quad * 4 + r;
                int col = colBase + wn + bn * 16 + lane16;
                float v = acc[am][bn][r] + bias[col];
                if (OUT_F32) ((float*)Cv)[(long long)row * N + col] = v;
                else         ((u16*)Cv)[(long long)row * N + col] = f2bf(v);
            }
}

// ---------------------------------------------------------------------------
// MFMA flash attention (unchanged from R12: pipelined + load-balance remap).
// ---------------------------------------------------------------------------
__global__ __launch_bounds__(256) void attn_mfma(const u16* __restrict__ Q,
                                                 const u16* __restrict__ Kb,
                                                 const u16* __restrict__ Vb,
                                                 u16* __restrict__ Ctx) {
    __shared__ u16 Vt[2][64 * 80];
    __shared__ u16 Ps[4][16 * 80];
    const int tid = threadIdx.x;
    const int wave = tid >> 6, lane = tid & 63;
    const int lane16 = lane & 15, quad = lane >> 4;
    const int idx_ = blockIdx.x;
    const int qhat = idx_ & 15;
    const int h  = (idx_ >> 4) & 15;
    const int b  = idx_ >> 8;
    const int qt = b ? (15 - qhat) : qhat;   // load-balance remap
    const int l0 = qt * 64;
    const int wq = wave * 16;
    const float scale = 0.125f;
    const int ntile = 3 * (qt + 1);

    bf16x8 qf[2];
    {
        const u16* qrow = Q + ((long long)(b * 1024 + l0 + wq + lane16)) * 1024 + h * 64;
        qf[0] = __builtin_bit_cast(bf16x8, *(const u16x8*)(qrow + quad * 8));
        qf[1] = __builtin_bit_cast(bf16x8, *(const u16x8*)(qrow + 32 + quad * 8));
    }

    const int skey = tid >> 2, sdb = (tid & 3) * 16;
    const long long bh = ((long long)b * 3072) * 1024 + h * 64;

    u16x8 kr[8], vr0, vr1;
    {
        long long o = bh;
        vr0 = *(const u16x8*)(Vb + o + (long long)skey * 1024 + sdb);
        vr1 = *(const u16x8*)(Vb + o + (long long)skey * 1024 + sdb + 8);
        #pragma unroll
        for (int c = 0; c < 2; c++)
            #pragma unroll
            for (int mi = 0; mi < 4; mi++)
                kr[c * 4 + mi] = *(const u16x8*)(Kb + o + (long long)(mi * 16 + lane16) * 1024 + c * 32 + quad * 8);
    }
    #pragma unroll
    for (int i = 0; i < 8; i++) {
        Vt[0][(sdb + i) * 80 + skey]     = vr0[i];
        Vt[0][(sdb + 8 + i) * 80 + skey] = vr1[i];
    }
    __syncthreads();

    float m_i = -1e30f, l_i = 0.f;
    floatx4 o_acc[4];
    #pragma unroll
    for (int mi = 0; mi < 4; mi++) o_acc[mi] = floatx4{0.f, 0.f, 0.f, 0.f};

    int seg = 0, t = 0;
    for (int idx = 0; idx < ntile; idx++) {
        const int cur = idx & 1;
        const bool haveNext = (idx + 1) < ntile;
        int nseg = seg, nt_ = t + 1;
        if (nt_ > qt) { nt_ = 0; nseg = seg + 1; }

        u16x8 nkr[8], nvr0, nvr1;
        if (haveNext) {
            long long o = bh + ((long long)(nseg * 1024 + nt_ * 64)) * 1024;
            nvr0 = *(const u16x8*)(Vb + o + (long long)skey * 1024 + sdb);
            nvr1 = *(const u16x8*)(Vb + o + (long long)skey * 1024 + sdb + 8);
            #pragma unroll
            for (int c = 0; c < 2; c++)
                #pragma unroll
                for (int mi = 0; mi < 4; mi++)
                    nkr[c * 4 + mi] = *(const u16x8*)(Kb + o + (long long)(mi * 16 + lane16) * 1024 + c * 32 + quad * 8);
        }

        floatx4 sacc[4];
        #pragma unroll
        for (int mi = 0; mi < 4; mi++) sacc[mi] = floatx4{0.f, 0.f, 0.f, 0.f};
        #pragma unroll
        for (int c = 0; c < 2; c++)
            #pragma unroll
            for (int mi = 0; mi < 4; mi++)
                sacc[mi] = __builtin_amdgcn_mfma_f32_16x16x32_bf16(
                    __builtin_bit_cast(bf16x8, kr[c * 4 + mi]), qf[c], sacc[mi], 0, 0, 0);

        const bool diag = (t == qt);
        const int qloc = wq + lane16;
        float tmax = -1e30f;
        #pragma unroll
        for (int mi = 0; mi < 4; mi++)
            #pragma unroll
            for (int r = 0; r < 4; r++) {
                float s = sacc[mi][r] * scale;
                if (diag && (mi * 16 + quad * 4 + r) > qloc) s = -1e30f;
                sacc[mi][r] = s;
                tmax = fmaxf(tmax, s);
            }
        tmax = fmaxf(tmax, __shfl_xor(tmax, 16));
        tmax = fmaxf(tmax, __shfl_xor(tmax, 32));
        float m_new = fmaxf(m_i, tmax);
        float alpha = __expf(m_i - m_new);
        float psum = 0.f;
        #pragma unroll
        for (int mi = 0; mi < 4; mi++)
            #pragma unroll
            for (int r = 0; r < 4; r++) {
                float p = __expf(sacc[mi][r] - m_new);
                psum += p;
                Ps[wave][lane16 * 80 + mi * 16 + quad * 4 + r] = f2bf(p);
            }
        psum += __shfl_xor(psum, 16);
        psum += __shfl_xor(psum, 32);
        m_i = m_new;
        l_i = l_i * alpha + psum;
        #pragma unroll
        for (int mi = 0; mi < 4; mi++)
            #pragma unroll
            for (int r = 0; r < 4; r++) o_acc[mi][r] *= alpha;

        __builtin_amdgcn_wave_barrier();

        #pragma unroll
        for (int c = 0; c < 2; c++) {
            bf16x8 pf = __builtin_bit_cast(bf16x8,
                *(const u16x8*)&Ps[wave][lane16 * 80 + c * 32 + quad * 8]);
            #pragma unroll
            for (int mi = 0; mi < 4; mi++) {
                bf16x8 vf = __builtin_bit_cast(bf16x8,
                    *(const u16x8*)&Vt[cur][(mi * 16 + lane16) * 80 + c * 32 + quad * 8]);
                o_acc[mi] = __builtin_amdgcn_mfma_f32_16x16x32_bf16(vf, pf, o_acc[mi], 0, 0, 0);
            }
        }

        if (haveNext) {
            #pragma unroll
            for (int i = 0; i < 8; i++) {
                Vt[cur ^ 1][(sdb + i) * 80 + skey]     = nvr0[i];
                Vt[cur ^ 1][(sdb + 8 + i) * 80 + skey] = nvr1[i];
            }
            #pragma unroll
            for (int i = 0; i < 8; i++) kr[i] = nkr[i];
            __syncthreads();
        }
        seg = nseg; t = nt_;
    }

    const float inv_l = 1.0f / l_i;
    long long crow = ((long long)(b * 1024 + l0 + wq + lane16)) * 1024 + h * 64;
    #pragma unroll
    for (int mi = 0; mi < 4; mi++)
        #pragma unroll
        for (int r = 0; r < 4; r++)
            Ctx[crow + mi * 16 + quad * 4 + r] = f2bf(o_acc[mi][r] * inv_l);
}

// ---------------------------------------------------------------------------
// residual + LayerNorm + mask. One block per row. fp32 in, fp32 out.
// ---------------------------------------------------------------------------
__global__ __launch_bounds__(256) void ln_kernel(const float* __restrict__ AO,
                                                 const float* __restrict__ HQ,
                                                 const float* __restrict__ g,
                                                 const float* __restrict__ bb,
                                                 const float* __restrict__ mask,
                                                 float* __restrict__ Out) {
    const int row = blockIdx.x;
    const int t = threadIdx.x;
    const int base = row * 1024 + t * 4;
    floatx4 a  = *(const floatx4*)&AO[base];
    floatx4 hq = *(const floatx4*)&HQ[base];
    float x[4];
    #pragma unroll
    for (int i = 0; i < 4; i++) x[i] = a[i] + hq[i];
    float s = x[0] + x[1] + x[2] + x[3];
    float ss = x[0]*x[0] + x[1]*x[1] + x[2]*x[2] + x[3]*x[3];
    #pragma unroll
    for (int off = 32; off >= 1; off >>= 1) { s += __shfl_xor(s, off); ss += __shfl_xor(ss, off); }
    __shared__ float smem[8];
    int wave = t >> 6, lane = t & 63;
    if (lane == 0) { smem[wave] = s; smem[4 + wave] = ss; }
    __syncthreads();
    s  = smem[0] + smem[1] + smem[2] + smem[3];
    ss = smem[4] + smem[5] + smem[6] + smem[7];
    float mu  = s * (1.f / 1024.f);
    float var = ss * (1.f / 1024.f) - mu * mu;
    float rs  = rsqrtf(var + 1e-5f);
    float mv  = mask[row];
    floatx4 g4 = *(const floatx4*)&g[t * 4];
    floatx4 b4 = *(const floatx4*)&bb[t * 4];
    floatx4 y4;
    #pragma unroll
    for (int i = 0; i < 4; i++) y4[i] = ((x[i] - mu) * rs * g4[i] + b4[i]) * mv;
    *(floatx4*)&Out[base] = y4;
}

// ---------------------------------------------------------------------------
// Workspace: 28 MB (proven safe).
//   ws+0      q_b (4 MB bf16) -> ctx in-place
//   ws+4 MB   k_b (12 MB bf16) -> ao (fp32 8 MB) after attention
//   ws+16 MB  v_b (12 MB bf16)   [contiguous after k_b: gemm_kv splits K|V]
// ---------------------------------------------------------------------------
extern "C" void kernel_launch(void* const* d_in, const int* in_sizes, int n_in,
                              void* d_out, int out_size, void* d_ws, size_t ws_size,
                              hipStream_t stream) {
    (void)in_sizes; (void)n_in; (void)out_size; (void)ws_size;
    const float* h_q   = (const float*)d_in[0];
    const float* h_kv1 = (const float*)d_in[1];
    const float* h_kv2 = (const float*)d_in[2];
    const float* maskp = (const float*)d_in[3];
    const float* win   = (const float*)d_in[4];
    const float* binp  = (const float*)d_in[5];
    const float* wout  = (const float*)d_in[6];
    const float* bout  = (const float*)d_in[7];
    const float* ln_g  = (const float*)d_in[8];
    const float* ln_b  = (const float*)d_in[9];
    float* outp = (float*)d_out;

    char* ws = (char*)d_ws;
    const size_t MB = 1024 * 1024;
    u16*   q_b   = (u16*)(ws);             // 4 MB; becomes ctx in-place
    u16*   k_b   = (u16*)(ws + 4 * MB);    // 12 MB; v_b directly after
    u16*   v_b   = (u16*)(ws + 16 * MB);   // 12 MB
    u16*   ctx_b = q_b;                    // alias (safe)
    float* ao    = (float*)(ws + 4 * MB);  // overwrites k_b after attn

    gemm128<0, false><<<dim3(16, 16), 256, 0, stream>>>(h_q, win, binp, (void*)q_b);
    gemm_kv<<<dim3(16, 48), 256, 0, stream>>>(h_kv1, h_kv2, win + 1024 * 1024, binp + 1024, k_b);
    attn_mfma<<<512, 256, 0, stream>>>(q_b, k_b, v_b, ctx_b);
    gemm128<2, true><<<dim3(16, 16), 256, 0, stream>>>(ctx_b, wout, bout, (void*)ao);
    ln_kernel<<<2048, 256, 0, stream>>>(ao, h_q, ln_g, ln_b, maskp, outp);
}